// Round 7
// baseline (423.241 us; speedup 1.0000x reference)
//
#include <hip/hip_runtime.h>
#include <hip/hip_bf16.h>

#define N_NODES 50000
#define N_EDGES 800000
#define DIM 128
#define SCAN_BLOCKS ((N_NODES + 255) / 256)   // 196
#define GBN 64                                 // nodes per gemm block
#define KT 16                                  // k-tile for W staging

// ---------------- CSR build (per launch; graph-capture safe) ----------------

__global__ __launch_bounds__(256) void hist_k(
    const int* __restrict__ dst, int* __restrict__ deg)
{
  int e = blockIdx.x * 256 + threadIdx.x;
  if (e < N_EDGES) atomicAdd(deg + dst[e], 1);
}

__global__ __launch_bounds__(256) void scan_part_k(
    const int* __restrict__ deg, int* __restrict__ excl,
    int* __restrict__ blocksum)
{
  int t = threadIdx.x, lane = t & 63, w = t >> 6;
  int idx = blockIdx.x * 256 + t;
  int v = (idx < N_NODES) ? deg[idx] : 0;
  int inc = v;
  #pragma unroll
  for (int off = 1; off < 64; off <<= 1) {
    int y = __shfl_up(inc, off, 64);
    if (lane >= off) inc += y;
  }
  __shared__ int wsum[4];
  if (lane == 63) wsum[w] = inc;
  __syncthreads();
  int wpre = 0;
  #pragma unroll
  for (int i = 0; i < 4; i++) if (i < w) wpre += wsum[i];
  if (idx < N_NODES) excl[idx] = wpre + inc - v;
  if (t == 255) blocksum[blockIdx.x] = wpre + inc;
}

__global__ __launch_bounds__(256) void scan_tops_k(
    const int* __restrict__ blocksum, int* __restrict__ tops)
{
  int t = threadIdx.x, lane = t & 63, w = t >> 6;
  int v = (t < SCAN_BLOCKS) ? blocksum[t] : 0;
  int inc = v;
  #pragma unroll
  for (int off = 1; off < 64; off <<= 1) {
    int y = __shfl_up(inc, off, 64);
    if (lane >= off) inc += y;
  }
  __shared__ int wsum[4];
  if (lane == 63) wsum[w] = inc;
  __syncthreads();
  int wpre = 0;
  #pragma unroll
  for (int i = 0; i < 4; i++) if (i < w) wpre += wsum[i];
  if (t < SCAN_BLOCKS) tops[t] = wpre + inc - v;
}

__global__ __launch_bounds__(256) void scan_add_k(
    const int* __restrict__ excl, const int* __restrict__ tops,
    int* __restrict__ row_start, int* __restrict__ cursor)
{
  int idx = blockIdx.x * 256 + threadIdx.x;
  if (idx < N_NODES) {
    int r = excl[idx] + tops[blockIdx.x];
    row_start[idx] = r;
    cursor[idx] = r;
  }
  if (idx == 0) row_start[N_NODES] = N_EDGES;
}

__global__ __launch_bounds__(256) void scatter_k(
    const int* __restrict__ src, const int* __restrict__ dst,
    int* __restrict__ cursor, int* __restrict__ csr_src)
{
  int e = blockIdx.x * 256 + threadIdx.x;
  if (e >= N_EDGES) return;
  int pos = atomicAdd(cursor + dst[e], 1);
  csr_src[pos] = src[e];
}

// ---------------- dense phase ----------------
// Dual GEMM v3: block = 64 nodes; wave = 16 nodes; lane = 4 of 256 combined
// out dims (lane<32 -> Wl dims 4l.., lane>=32 -> Wr dims 4l-128..). x tile
// [64][128] (32 KB) staged once; W tile [16][256] (16 KB) staged per k-tile.
// Compute: x reads are same-address b128 broadcasts (free), W reads are
// stride-1 b128 (conflict-free). 48 KB LDS -> 3 blocks/CU.
__global__ __launch_bounds__(256) void gemm_dual(
    const float* __restrict__ x,
    const float* __restrict__ Wl, const float* __restrict__ bl,
    const float* __restrict__ Wr, const float* __restrict__ br,
    float* __restrict__ xl, float* __restrict__ xr)
{
  __shared__ float xs[GBN][DIM];     // 32 KB
  __shared__ float wt[KT][256];      // 16 KB
  int tid = threadIdx.x;
  int n0 = blockIdx.x * GBN;

  // stage x: 64 nodes x 32 float4 = 2048 f4, 8 per thread
  #pragma unroll
  for (int it = 0; it < 8; it++) {
    int fid = tid + 256 * it;
    int n = fid >> 5, k4 = fid & 31;
    int gn = n0 + n;
    float4 val = make_float4(0.f, 0.f, 0.f, 0.f);
    if (gn < N_NODES) val = *(const float4*)(x + (size_t)gn*DIM + k4*4);
    *(float4*)(&xs[n][k4*4]) = val;
  }

  int wv = tid >> 6;                 // wave id 0..3 -> node group
  int lane = tid & 63;
  int nbase = wv * 16;

  float acc[16][4];
  #pragma unroll
  for (int i = 0; i < 16; i++)
    #pragma unroll
    for (int c = 0; c < 4; c++) acc[i][c] = 0.f;

  for (int kt = 0; kt < DIM / KT; kt++) {
    __syncthreads();                 // xs ready (kt=0) / prev wt reads done
    // stage W tile: 16 rows x 64 f4 = 1024 f4, 4 per thread
    #pragma unroll
    for (int it = 0; it < 4; it++) {
      int fid = tid + 256 * it;
      int k = fid >> 6, cf4 = fid & 63;
      const float* srcw = (cf4 < 32)
          ? (Wl + (size_t)(kt*KT + k)*DIM + cf4*4)
          : (Wr + (size_t)(kt*KT + k)*DIM + (cf4-32)*4);
      *(float4*)(&wt[k][cf4*4]) = *(const float4*)srcw;
    }
    __syncthreads();

    #pragma unroll
    for (int k4 = 0; k4 < KT/4; k4++) {
      float4 w0 = *(const float4*)(&wt[k4*4+0][lane*4]);
      float4 w1 = *(const float4*)(&wt[k4*4+1][lane*4]);
      float4 w2 = *(const float4*)(&wt[k4*4+2][lane*4]);
      float4 w3 = *(const float4*)(&wt[k4*4+3][lane*4]);
      #pragma unroll
      for (int i = 0; i < 16; i++) {
        float4 xv = *(const float4*)(&xs[nbase + i][kt*KT + k4*4]);
        acc[i][0] = fmaf(xv.x, w0.x, acc[i][0]);
        acc[i][1] = fmaf(xv.x, w0.y, acc[i][1]);
        acc[i][2] = fmaf(xv.x, w0.z, acc[i][2]);
        acc[i][3] = fmaf(xv.x, w0.w, acc[i][3]);
        acc[i][0] = fmaf(xv.y, w1.x, acc[i][0]);
        acc[i][1] = fmaf(xv.y, w1.y, acc[i][1]);
        acc[i][2] = fmaf(xv.y, w1.z, acc[i][2]);
        acc[i][3] = fmaf(xv.y, w1.w, acc[i][3]);
        acc[i][0] = fmaf(xv.z, w2.x, acc[i][0]);
        acc[i][1] = fmaf(xv.z, w2.y, acc[i][1]);
        acc[i][2] = fmaf(xv.z, w2.z, acc[i][2]);
        acc[i][3] = fmaf(xv.z, w2.w, acc[i][3]);
        acc[i][0] = fmaf(xv.w, w3.x, acc[i][0]);
        acc[i][1] = fmaf(xv.w, w3.y, acc[i][1]);
        acc[i][2] = fmaf(xv.w, w3.z, acc[i][2]);
        acc[i][3] = fmaf(xv.w, w3.w, acc[i][3]);
      }
    }
  }

  bool left = lane < 32;
  int d = left ? lane*4 : lane*4 - 128;
  const float* B = left ? bl : br;
  float* outp = left ? xl : xr;
  float4 bv = *(const float4*)(B + d);
  #pragma unroll
  for (int i = 0; i < 16; i++) {
    int n = n0 + nbase + i;
    if (n < N_NODES) {
      float4 o = make_float4(acc[i][0] + bv.x, acc[i][1] + bv.y,
                             acc[i][2] + bv.z, acc[i][3] + bv.w);
      *(float4*)(outp + (size_t)n*DIM + d) = o;
    }
  }
}

// ---------------- fused edge phase: 32 lanes/node, 2 nodes/wave ------------
__global__ __launch_bounds__(256) void gat_gather(
    const float* __restrict__ xl, const float* __restrict__ xr,
    const int* __restrict__ row_start, const int* __restrict__ csr_src,
    const float* __restrict__ att, const float* __restrict__ bias,
    float* __restrict__ out)
{
  int wave = (blockIdx.x * 256 + threadIdx.x) >> 6;
  int lane = threadIdx.x & 63;
  int half = lane >> 5;
  int hl = lane & 31;
  int node = wave * 2 + half;
  bool valid = node < N_NODES;
  int nc = valid ? node : (N_NODES - 1);
  int r0 = row_start[nc], r1 = row_start[nc + 1];
  int deg = valid ? (r1 - r0) : 0;
  int last = r0 + deg - 1;
  int dmax = max(deg, __shfl_xor(deg, 32, 64));   // max over the 2 nodes

  float4 xrv = *(const float4*)(xr + (size_t)nc*DIM + hl*4);
  float4 av  = *(const float4*)(att + hl*4);
  float m = -INFINITY, l = 0.f;
  float4 acc = make_float4(0.f, 0.f, 0.f, 0.f);

  for (int t = 0; t < dmax; t += 8) {
    float4 v[8];
    float p[8];
    #pragma unroll
    for (int j = 0; j < 8; j++) {
      int rr = r0 + t + j;
      int rc = rr <= last ? rr : last;
      rc = rc >= 0 ? rc : 0;                       // deg==0 safety
      int si = csr_src[rc];
      v[j] = *(const float4*)(xl + (size_t)si*DIM + hl*4);
    }
    #pragma unroll
    for (int j = 0; j < 8; j++) {
      float s0 = v[j].x + xrv.x, s1 = v[j].y + xrv.y;
      float s2 = v[j].z + xrv.z, s3 = v[j].w + xrv.w;
      s0 = s0 > 0.f ? s0 : 0.2f*s0;
      s1 = s1 > 0.f ? s1 : 0.2f*s1;
      s2 = s2 > 0.f ? s2 : 0.2f*s2;
      s3 = s3 > 0.f ? s3 : 0.2f*s3;
      p[j] = av.x*s0 + av.y*s1 + av.z*s2 + av.w*s3;
    }
    #pragma unroll
    for (int o = 1; o <= 16; o <<= 1) {            // stays within 32-half
      #pragma unroll
      for (int j = 0; j < 8; j++) p[j] += __shfl_xor(p[j], o, 64);
    }
    #pragma unroll
    for (int j = 0; j < 8; j++) if (t + j >= deg) p[j] = -INFINITY;
    float pmax = p[0];
    #pragma unroll
    for (int j = 1; j < 8; j++) pmax = fmaxf(pmax, p[j]);
    float mn = fmaxf(m, pmax);
    float sc = (mn == -INFINITY) ? 0.f : __expf(m - mn);
    l *= sc; acc.x *= sc; acc.y *= sc; acc.z *= sc; acc.w *= sc;
    #pragma unroll
    for (int j = 0; j < 8; j++) {
      float w = (t + j < deg) ? __expf(p[j] - mn) : 0.f;
      l += w;
      acc.x = fmaf(w, v[j].x, acc.x);
      acc.y = fmaf(w, v[j].y, acc.y);
      acc.z = fmaf(w, v[j].z, acc.z);
      acc.w = fmaf(w, v[j].w, acc.w);
    }
    m = mn;
  }

  if (valid) {
    float denom = fmaxf(l, 1e-16f);
    float4 bv = *(const float4*)(bias + hl*4);
    float4 ov;
    ov.x = fmaxf(acc.x / denom + bv.x, 0.f);
    ov.y = fmaxf(acc.y / denom + bv.y, 0.f);
    ov.z = fmaxf(acc.z / denom + bv.z, 0.f);
    ov.w = fmaxf(acc.w / denom + bv.w, 0.f);
    *(float4*)(out + (size_t)node*DIM + hl*4) = ov;
  }
}

extern "C" void kernel_launch(void* const* d_in, const int* in_sizes, int n_in,
                              void* d_out, int out_size, void* d_ws, size_t ws_size,
                              hipStream_t stream)
{
  const float* node_fts = (const float*)d_in[0];
  const int*  edge_index = (const int*)d_in[1];
  const float* Wl1 = (const float*)d_in[2];
  const float* bl1 = (const float*)d_in[3];
  const float* Wr1 = (const float*)d_in[4];
  const float* br1 = (const float*)d_in[5];
  const float* att1 = (const float*)d_in[6];
  const float* bias1 = (const float*)d_in[7];
  const float* Wl2 = (const float*)d_in[8];
  const float* bl2 = (const float*)d_in[9];
  const float* Wr2 = (const float*)d_in[10];
  const float* br2 = (const float*)d_in[11];
  const float* att2 = (const float*)d_in[12];
  const float* bias2 = (const float*)d_in[13];
  const int* src = edge_index;
  const int* dst = edge_index + N_EDGES;

  float* xl = (float*)d_ws;                       // N*D
  float* xr = xl + (size_t)N_NODES*DIM;           // N*D
  float* h  = xr + (size_t)N_NODES*DIM;           // N*D
  int* deg       = (int*)(h + (size_t)N_NODES*DIM);
  int* row_start = deg + N_NODES;                 // N+1
  int* cursor    = row_start + N_NODES + 1;       // N
  int* csr_src   = cursor + N_NODES;              // E
  int* excl      = csr_src + N_EDGES;             // N
  int* blocksum  = excl + N_NODES;                // SCAN_BLOCKS
  int* tops      = blocksum + SCAN_BLOCKS;        // SCAN_BLOCKS

  int eb = (N_EDGES + 255) / 256;
  int gemm_blocks = (N_NODES + GBN - 1) / GBN;
  int gather_waves = (N_NODES + 1) / 2;
  int gather_blocks = (gather_waves + 3) / 4;     // 4 waves/block

  // ---- CSR build (edge_index is identical for both layers) ----
  hipMemsetAsync(deg, 0, N_NODES * sizeof(int), stream);
  hist_k<<<eb, 256, 0, stream>>>(dst, deg);
  scan_part_k<<<SCAN_BLOCKS, 256, 0, stream>>>(deg, excl, blocksum);
  scan_tops_k<<<1, 256, 0, stream>>>(blocksum, tops);
  scan_add_k<<<SCAN_BLOCKS, 256, 0, stream>>>(excl, tops, row_start, cursor);
  scatter_k<<<eb, 256, 0, stream>>>(src, dst, cursor, csr_src);

  // ---- layer 1 ----
  gemm_dual<<<gemm_blocks, 256, 0, stream>>>(node_fts, Wl1, bl1, Wr1, br1, xl, xr);
  gat_gather<<<gather_blocks, 256, 0, stream>>>(xl, xr, row_start, csr_src, att1, bias1, h);

  // ---- layer 2 ----
  gemm_dual<<<gemm_blocks, 256, 0, stream>>>(h, Wl2, bl2, Wr2, br2, xl, xr);
  gat_gather<<<gather_blocks, 256, 0, stream>>>(xl, xr, row_start, csr_src, att2, bias2, (float*)d_out);
}